// Round 5
// baseline (201.560 us; speedup 1.0000x reference)
//
#include <hip/hip_runtime.h>

// ---------------------------------------------------------------------------
// AttentionHead: out = softmax(mask(q k^T / sqrt(384))) v, q/k/v = x @ W{q,k,v}
// B=256, T=256, C=384, H=64.
// All intermediates FRAG-LINEAR: lane l's 16-B MFMA fragment at chunk + l*16,
// so every fragment load/store is one coalesced 1-KB transaction.
//   Wt_sw : [kc:12][nt:12][lane:64][j:8]  (nt<4: q-feats x 1/sqrt(384), <8: k, else v)
//   q_sw/k_sw : per batch [tile:16][kc:2][lane:64][j:8]
//   v_sw  : per batch [kc:8][nt:4][lane:64][j:8]  (V^T fragments)
// attn v4: S^T = MFMA(A=K,B=Q) so the P C->A-layout transform is 8 shuffles
// per 32-chunk in registers. ZERO LDS in all kernels. Native v_cvt_pk_bf16_f32
// conversions via __builtin_convertvector.
// ---------------------------------------------------------------------------

typedef short s16x8 __attribute__((ext_vector_type(8)));   // 8 x bf16 raw bits
typedef float f32x4 __attribute__((ext_vector_type(4)));
typedef float f32x2 __attribute__((ext_vector_type(2)));
typedef unsigned u32x4 __attribute__((ext_vector_type(4)));
typedef __bf16 bf16x2t __attribute__((ext_vector_type(2)));

#define MFMA16(a, b, c) __builtin_amdgcn_mfma_f32_16x16x32_bf16((a), (b), (c), 0, 0, 0)

__device__ __forceinline__ unsigned short f2bf(float f) {
  return __builtin_bit_cast(unsigned short, (__bf16)f);     // v_cvt_pk_bf16_f32 (RNE)
}
__device__ __forceinline__ unsigned cvt2(float a, float b) { // 2 f32 -> packed bf16x2
  f32x2 t; t[0] = a; t[1] = b;
  bf16x2t r = __builtin_convertvector(t, bf16x2t);
  return __builtin_bit_cast(unsigned, r);
}
__device__ __forceinline__ s16x8 cvt8(float4 a, float4 b) { // 8 f32 -> bf16 frag
  u32x4 u;
  u[0] = cvt2(a.x, a.y); u[1] = cvt2(a.z, a.w);
  u[2] = cvt2(b.x, b.y); u[3] = cvt2(b.z, b.w);
  return __builtin_bit_cast(s16x8, u);
}

// ---------------------------------------------------------------------------
// Kernel 0: build frag-linear Wt_sw from fp32 Wq/Wk/Wv.
// ---------------------------------------------------------------------------
__global__ __launch_bounds__(256) void wcvt(
    const float* __restrict__ Wq, const float* __restrict__ Wk,
    const float* __restrict__ Wv, unsigned short* __restrict__ Wt_sw) {
  int idx = blockIdx.x * 256 + threadIdx.x;   // 73728 = 12*12*64*8
  int j = idx & 7;
  int c = idx >> 3;
  int n15 = c & 15;
  int q4 = (c >> 4) & 3;
  int g = c >> 6;
  int nt = g % 12;
  int kc = g / 12;
  int n = nt * 16 + n15;                      // output feature 0..191
  int kk = kc * 32 + q4 * 8 + j;              // reduction index 0..383
  const float* src = (n < 64) ? Wq : (n < 128) ? Wk : Wv;
  float v = src[kk * 64 + (n & 63)];
  if (n < 64) v *= 0.05103103630798287f;      // fold 1/sqrt(384) into Wq
  Wt_sw[idx] = f2bf(v);
}

// ---------------------------------------------------------------------------
// Kernel 1: rows = 65536, K = 384. Grid 512 x 4 waves, 32 rows/wave.
// q/k: MFMA(A=W, B=x) -> lane holds 4 consecutive features of one token.
// v:   MFMA(A=x, B=W) -> lane holds 4 consecutive tokens of one feature.
// 1-deep prefetch of x (HBM/L3) and all 12 W frags (L2). Frag-linear stores.
// ---------------------------------------------------------------------------
__global__ __launch_bounds__(256, 2) void qkv_proj(
    const float* __restrict__ x, const unsigned short* __restrict__ Wt_sw,
    unsigned short* __restrict__ q_sw, unsigned short* __restrict__ k_sw,
    unsigned short* __restrict__ v_sw) {
  const int tid = threadIdx.x;
  const int lane = tid & 63;
  const int wv = tid >> 6;
  const int n15 = lane & 15;
  const int q4 = lane >> 4;
  const long row0 = (long)blockIdx.x * 128 + wv * 32;

  f32x4 acc[12][2];
#pragma unroll
  for (int i = 0; i < 12; ++i)
#pragma unroll
    for (int t = 0; t < 2; ++t) acc[i][t] = (f32x4){0.f, 0.f, 0.f, 0.f};

  const float* xp0 = x + (row0 + n15) * 384 + q4 * 8;
  const float* xp1 = x + (row0 + 16 + n15) * 384 + q4 * 8;
  float4 c00 = *reinterpret_cast<const float4*>(xp0);
  float4 c01 = *reinterpret_cast<const float4*>(xp0 + 4);
  float4 c10 = *reinterpret_cast<const float4*>(xp1);
  float4 c11 = *reinterpret_cast<const float4*>(xp1 + 4);

  s16x8 wc[12];
#pragma unroll
  for (int nt = 0; nt < 12; ++nt)
    wc[nt] = *reinterpret_cast<const s16x8*>(Wt_sw + nt * 512 + lane * 8);

  for (int kc = 0; kc < 12; ++kc) {
    const int nkc = (kc < 11) ? kc + 1 : 11;  // clamped prefetch
    float4 p00 = *reinterpret_cast<const float4*>(xp0 + nkc * 32);
    float4 p01 = *reinterpret_cast<const float4*>(xp0 + nkc * 32 + 4);
    float4 p10 = *reinterpret_cast<const float4*>(xp1 + nkc * 32);
    float4 p11 = *reinterpret_cast<const float4*>(xp1 + nkc * 32 + 4);
    s16x8 wn[12];
#pragma unroll
    for (int nt = 0; nt < 12; ++nt)
      wn[nt] = *reinterpret_cast<const s16x8*>(Wt_sw + (nkc * 12 + nt) * 512 + lane * 8);

    s16x8 xa[2];
    xa[0] = cvt8(c00, c01);
    xa[1] = cvt8(c10, c11);

#pragma unroll
    for (int nt = 0; nt < 12; ++nt) {
#pragma unroll
      for (int t = 0; t < 2; ++t) {
        if (nt < 8) acc[nt][t] = MFMA16(wc[nt], xa[t], acc[nt][t]);  // q/k
        else        acc[nt][t] = MFMA16(xa[t], wc[nt], acc[nt][t]);  // v
      }
    }
    c00 = p00; c01 = p01; c10 = p10; c11 = p11;
#pragma unroll
    for (int nt = 0; nt < 12; ++nt) wc[nt] = wn[nt];
  }

  // Epilogue: frag-linear swizzled q/k/v (8-B packed stores).
  const long bb_ = row0 >> 8;
  unsigned short* qb = q_sw + bb_ * 16384;
  unsigned short* kb = k_sw + bb_ * 16384;
  unsigned short* vb = v_sw + bb_ * 16384;
#pragma unroll
  for (int t = 0; t < 2; ++t) {
    const int rb = (int)(row0 & 255) + t * 16;   // batch-local token base
    const int qtile = rb >> 4;
    // q/k: token = rb + n15, feature f = mt*16 + q4*4 + e
#pragma unroll
    for (int mt = 0; mt < 4; ++mt) {
      const int off = ((qtile * 2 + (mt >> 1)) * 64 + (2 * (mt & 1) + (q4 >> 1)) * 16 + n15) * 8
                      + (q4 & 1) * 4;
      uint2 sq, sk;
      sq.x = cvt2(acc[mt][t][0], acc[mt][t][1]);
      sq.y = cvt2(acc[mt][t][2], acc[mt][t][3]);
      sk.x = cvt2(acc[4 + mt][t][0], acc[4 + mt][t][1]);
      sk.y = cvt2(acc[4 + mt][t][2], acc[4 + mt][t][3]);
      *reinterpret_cast<uint2*>(qb + off) = sq;
      *reinterpret_cast<uint2*>(kb + off) = sk;
    }
    // v: token s = s0 + e (s0 = rb + q4*4), feature h = nt*16 + n15
    const int s0 = rb + q4 * 4;
#pragma unroll
    for (int nt = 0; nt < 4; ++nt) {
      const int off = (((s0 >> 5) * 4 + nt) * 64 + ((s0 >> 3) & 3) * 16 + n15) * 8 + (s0 & 7);
      uint2 sv;
      sv.x = cvt2(acc[8 + nt][t][0], acc[8 + nt][t][1]);
      sv.y = cvt2(acc[8 + nt][t][2], acc[8 + nt][t][3]);
      *reinterpret_cast<uint2*>(vb + off) = sv;
    }
  }
}

// ---------------------------------------------------------------------------
// Kernel 2: grid 1024 = 4 sub-blocks x 256 batches; wave w of sub-block j
// owns q-tile {j, 7-j, 8+j, 15-j}[w] (equal work). ZERO LDS:
//   S^T tile = MFMA(A=K-frag, B=Q-frag)  -> lane: S^T[s=q4*4+e][m=n15]
//   p = exp(S^T) (no max pass; logits bounded), packed to bf16x2 pairs.
//   Row sum over s = Sum_e + shfl_xor(16,32)  (indexed by m=n15).
//   PV A-frag[m=n15][s=q4*8+j] assembled from two source lanes via 8 shuffles
//   + tile-pair cndmask (missing odd tail tile = zero). O = MFMA(pf, V^T-frag).
//   Normalizer broadcast back to C-layout rows with 4 shuffles.
// ---------------------------------------------------------------------------
__global__ __launch_bounds__(256) void attn(
    const unsigned short* __restrict__ q_sw, const unsigned short* __restrict__ k_sw,
    const unsigned short* __restrict__ v_sw, float* __restrict__ out) {
  const int b = blockIdx.x & 255;
  const int j = blockIdx.x >> 8;              // 0..3
  const int tid = threadIdx.x;
  const int wv = tid >> 6;
  const int lane = tid & 63;
  const int n15 = lane & 15;
  const int q4 = lane >> 4;

  const int qt = (wv == 0) ? j : (wv == 1) ? 7 - j : (wv == 2) ? 8 + j : 15 - j;

  const unsigned short* qb = q_sw + b * 16384;
  const unsigned short* kb = k_sw + b * 16384;
  const unsigned short* vb = v_sw + b * 16384;

  const s16x8 qf0 = *reinterpret_cast<const s16x8*>(qb + (qt * 2 + 0) * 512 + lane * 8);
  const s16x8 qf1 = *reinterpret_cast<const s16x8*>(qb + (qt * 2 + 1) * 512 + lane * 8);

  uint2 pk[16];              // packed exp(S^T) tiles: {bf16(p0,p1), bf16(p2,p3)}
  float psum = 0.f;
  s16x8 kf0 = *reinterpret_cast<const s16x8*>(kb + 0 * 512 + lane * 8);
  s16x8 kf1 = *reinterpret_cast<const s16x8*>(kb + 1 * 512 + lane * 8);
#pragma unroll 16
  for (int ct = 0; ct < 16; ++ct) {
    if (ct > qt) break;
    const int nc = (ct < qt) ? ct + 1 : ct;   // clamped prefetch (in-bounds)
    s16x8 nf0 = *reinterpret_cast<const s16x8*>(kb + (nc * 2 + 0) * 512 + lane * 8);
    s16x8 nf1 = *reinterpret_cast<const s16x8*>(kb + (nc * 2 + 1) * 512 + lane * 8);
    f32x4 a = (f32x4){0.f, 0.f, 0.f, 0.f};
    a = MFMA16(kf0, qf0, a);                  // S^T: rows s, cols m
    a = MFMA16(kf1, qf1, a);
    const bool diag = (ct == qt);
    float p[4];
#pragma unroll
    for (int e = 0; e < 4; ++e) {
      p[e] = (diag && (q4 * 4 + e > n15)) ? 0.f : __expf(a[e]);  // mask s > m
      psum += p[e];
    }
    pk[ct].x = cvt2(p[0], p[1]);
    pk[ct].y = cvt2(p[2], p[3]);
    kf0 = nf0; kf1 = nf1;
  }
  psum += __shfl_xor(psum, 16);
  psum += __shfl_xor(psum, 32);
  const float rn_col = 1.0f / psum;           // row sum for m = n15

  // O = P @ V with register-shuffle P-frag assembly; rolling V prefetch.
  f32x4 O[4];
#pragma unroll
  for (int nt = 0; nt < 4; ++nt) O[nt] = (f32x4){0.f, 0.f, 0.f, 0.f};
  const int nk = (qt + 2) >> 1;               // ceil(16*(qt+1)/32)
  s16x8 vf[4], vn[4];
#pragma unroll
  for (int nt = 0; nt < 4; ++nt)
    vf[nt] = *reinterpret_cast<const s16x8*>(vb + nt * 512 + lane * 8);
  const int laneA = ((q4 & 1) << 5) + n15;    // source lane for j=0..3
  const bool hi = (q4 >> 1) != 0;             // use tile 2kc+1 instead of 2kc
#pragma unroll 8
  for (int kc = 0; kc < 8; ++kc) {
    if (kc >= nk) break;
    const int ncc = (kc + 1 < nk) ? kc + 1 : kc;
#pragma unroll
    for (int nt = 0; nt < 4; ++nt)
      vn[nt] = *reinterpret_cast<const s16x8*>(vb + (ncc * 4 + nt) * 512 + lane * 8);
    const uint2 t0 = pk[2 * kc];
    const uint2 t1 = (2 * kc + 1 <= qt) ? pk[2 * kc + 1] : make_uint2(0u, 0u);
    // round 0: broadcast tile 2kc; round 1: tile 2kc+1; select by q4>>1
    unsigned r0a = __shfl(t0.x, laneA),      r0b = __shfl(t0.y, laneA);
    unsigned r0c = __shfl(t0.x, laneA + 16), r0d = __shfl(t0.y, laneA + 16);
    unsigned r1a = __shfl(t1.x, laneA),      r1b = __shfl(t1.y, laneA);
    unsigned r1c = __shfl(t1.x, laneA + 16), r1d = __shfl(t1.y, laneA + 16);
    u32x4 u;
    u[0] = hi ? r1a : r0a; u[1] = hi ? r1b : r0b;
    u[2] = hi ? r1c : r0c; u[3] = hi ? r1d : r0d;
    s16x8 pf = __builtin_bit_cast(s16x8, u);  // A[m=n15][s=32kc+q4*8+j]
#pragma unroll
    for (int nt = 0; nt < 4; ++nt) {
      O[nt] = MFMA16(pf, vf[nt], O[nt]);
      vf[nt] = vn[nt];
    }
  }
  float rnm[4];
#pragma unroll
  for (int e = 0; e < 4; ++e) rnm[e] = __shfl(rn_col, q4 * 4 + e);
#pragma unroll
  for (int nt = 0; nt < 4; ++nt)
#pragma unroll
    for (int e = 0; e < 4; ++e)
      out[(size_t)(b * 256 + qt * 16 + q4 * 4 + e) * 64 + nt * 16 + n15] = O[nt][e] * rnm[e];
}

extern "C" void kernel_launch(void* const* d_in, const int* in_sizes, int n_in,
                              void* d_out, int out_size, void* d_ws, size_t ws_size,
                              hipStream_t stream) {
  const float* x  = (const float*)d_in[0];
  const float* Wq = (const float*)d_in[1];
  const float* Wk = (const float*)d_in[2];
  const float* Wv = (const float*)d_in[3];
  float* out = (float*)d_out;

  // ws: q_sw | k_sw | v_sw (each 65536*64 bf16 = 8 MB) | Wt_sw (73728 bf16)
  unsigned short* q_sw = (unsigned short*)d_ws;
  unsigned short* k_sw = q_sw + (size_t)65536 * 64;
  unsigned short* v_sw = k_sw + (size_t)65536 * 64;
  unsigned short* Wt_sw = v_sw + (size_t)65536 * 64;

  wcvt<<<288, 256, 0, stream>>>(Wq, Wk, Wv, Wt_sw);
  qkv_proj<<<512, 256, 0, stream>>>(x, Wt_sw, q_sw, k_sw, v_sw);
  attn<<<1024, 256, 0, stream>>>(q_sw, k_sw, v_sw, out);
}

// Round 6
// 193.930 us; speedup vs baseline: 1.0393x; 1.0393x over previous
//
#include <hip/hip_runtime.h>

// ---------------------------------------------------------------------------
// AttentionHead: out = softmax(mask(q k^T / sqrt(384))) v, q/k/v = x @ W{q,k,v}
// B=256, T=256, C=384, H=64.
// FUSED: one block per batch (512 thr, 8 waves, 1 block/CU).
//   Phase 1: per-wave 32-token QKV projection (bf16 MFMA, W frags from
//            L2-resident frag-linear Wt_sw, 1-deep x prefetch); q/k/v stored
//            FRAG-LINEAR into LDS (96 KB).
//   Phase 2: per-wave q-tiles {w, 15-w} (balanced: 17 col-tiles each).
//            S^T = MFMA(A=K,B=Q) so P's C->A-layout transform is 8 register
//            shuffles per 32-chunk; exp fused (no max pass; logits bounded);
//            PV from LDS V^T frags. All frag reads are ds_read_b128.
// Frag-linear: lane l's 16-B fragment of chunk c at base + c*1024 + l*16.
//   Wt_sw : [kc:12][nt:12][lane:64][j:8] (nt<4: q-feats x 1/sqrt(384), <8: k, else v)
//   q/k LDS: [tile:16][kc:2][lane:64][j:8]   v LDS: [kc:8][nt:4][lane:64][j:8]
// ---------------------------------------------------------------------------

typedef short s16x8 __attribute__((ext_vector_type(8)));   // 8 x bf16 raw bits
typedef float f32x4 __attribute__((ext_vector_type(4)));
typedef float f32x2 __attribute__((ext_vector_type(2)));
typedef unsigned u32x4 __attribute__((ext_vector_type(4)));
typedef __bf16 bf16x2t __attribute__((ext_vector_type(2)));

#define MFMA16(a, b, c) __builtin_amdgcn_mfma_f32_16x16x32_bf16((a), (b), (c), 0, 0, 0)

__device__ __forceinline__ unsigned short f2bf(float f) {
  return __builtin_bit_cast(unsigned short, (__bf16)f);     // v_cvt bf16 (RNE)
}
__device__ __forceinline__ unsigned cvt2(float a, float b) { // 2 f32 -> packed bf16x2
  f32x2 t; t[0] = a; t[1] = b;
  bf16x2t r = __builtin_convertvector(t, bf16x2t);
  return __builtin_bit_cast(unsigned, r);
}
__device__ __forceinline__ s16x8 cvt8(float4 a, float4 b) { // 8 f32 -> bf16 frag
  u32x4 u;
  u[0] = cvt2(a.x, a.y); u[1] = cvt2(a.z, a.w);
  u[2] = cvt2(b.x, b.y); u[3] = cvt2(b.z, b.w);
  return __builtin_bit_cast(s16x8, u);
}

// ---------------------------------------------------------------------------
// Kernel 0: build frag-linear Wt_sw from fp32 Wq/Wk/Wv.
// ---------------------------------------------------------------------------
__global__ __launch_bounds__(256) void wcvt(
    const float* __restrict__ Wq, const float* __restrict__ Wk,
    const float* __restrict__ Wv, unsigned short* __restrict__ Wt_sw) {
  int idx = blockIdx.x * 256 + threadIdx.x;   // 73728 = 12*12*64*8
  int j = idx & 7;
  int c = idx >> 3;
  int n15 = c & 15;
  int q4 = (c >> 4) & 3;
  int g = c >> 6;
  int nt = g % 12;
  int kc = g / 12;
  int n = nt * 16 + n15;                      // output feature 0..191
  int kk = kc * 32 + q4 * 8 + j;              // reduction index 0..383
  const float* src = (n < 64) ? Wq : (n < 128) ? Wk : Wv;
  float v = src[kk * 64 + (n & 63)];
  if (n < 64) v *= 0.05103103630798287f;      // fold 1/sqrt(384) into Wq
  Wt_sw[idx] = f2bf(v);
}

// ---------------------------------------------------------------------------
// Fused kernel: one block per batch.
// ---------------------------------------------------------------------------
__global__ __launch_bounds__(512) void fused_attn(
    const float* __restrict__ x, const unsigned short* __restrict__ Wt_sw,
    float* __restrict__ out) {
  __shared__ unsigned short q_l[16384];   // 32 KB
  __shared__ unsigned short k_l[16384];   // 32 KB
  __shared__ unsigned short v_l[16384];   // 32 KB (V^T frags)
  const int b = blockIdx.x;
  const int tid = threadIdx.x;
  const int wv = tid >> 6;                // 0..7
  const int lane = tid & 63;
  const int n15 = lane & 15;
  const int q4 = lane >> 4;

  // ======================= Phase 1: QKV -> LDS =======================
  // Wave wv projects tokens rb0 .. rb0+31 (tiles 2wv, 2wv+1).
  {
    const int rb0 = wv * 32;
    f32x4 acc[12][2];
#pragma unroll
    for (int i = 0; i < 12; ++i)
#pragma unroll
      for (int t = 0; t < 2; ++t) acc[i][t] = (f32x4){0.f, 0.f, 0.f, 0.f};

    const float* xp0 = x + ((long)b * 256 + rb0 + n15) * 384 + q4 * 8;
    const float* xp1 = xp0 + 16 * 384;
    float4 c00 = *reinterpret_cast<const float4*>(xp0);
    float4 c01 = *reinterpret_cast<const float4*>(xp0 + 4);
    float4 c10 = *reinterpret_cast<const float4*>(xp1);
    float4 c11 = *reinterpret_cast<const float4*>(xp1 + 4);

    s16x8 wc[12];
#pragma unroll
    for (int nt = 0; nt < 12; ++nt)
      wc[nt] = *reinterpret_cast<const s16x8*>(Wt_sw + nt * 512 + lane * 8);

    for (int kc = 0; kc < 12; ++kc) {
      const int nkc = (kc < 11) ? kc + 1 : 11;  // clamped prefetch
      float4 p00 = *reinterpret_cast<const float4*>(xp0 + nkc * 32);
      float4 p01 = *reinterpret_cast<const float4*>(xp0 + nkc * 32 + 4);
      float4 p10 = *reinterpret_cast<const float4*>(xp1 + nkc * 32);
      float4 p11 = *reinterpret_cast<const float4*>(xp1 + nkc * 32 + 4);
      s16x8 wn[12];
#pragma unroll
      for (int nt = 0; nt < 12; ++nt)
        wn[nt] = *reinterpret_cast<const s16x8*>(Wt_sw + (nkc * 12 + nt) * 512 + lane * 8);

      s16x8 xa[2];
      xa[0] = cvt8(c00, c01);
      xa[1] = cvt8(c10, c11);

#pragma unroll
      for (int nt = 0; nt < 12; ++nt) {
#pragma unroll
        for (int t = 0; t < 2; ++t) {
          if (nt < 8) acc[nt][t] = MFMA16(wc[nt], xa[t], acc[nt][t]);  // q/k
          else        acc[nt][t] = MFMA16(xa[t], wc[nt], acc[nt][t]);  // v
        }
      }
      c00 = p00; c01 = p01; c10 = p10; c11 = p11;
#pragma unroll
      for (int nt = 0; nt < 12; ++nt) wc[nt] = wn[nt];
    }

    // Epilogue: frag-linear q/k/v into LDS (8-B packed stores).
#pragma unroll
    for (int t = 0; t < 2; ++t) {
      const int rb = rb0 + t * 16;
      const int qtile = rb >> 4;     // = 2*wv + t
      // q/k: token = rb + n15, feature f = mt*16 + q4*4 + e
#pragma unroll
      for (int mt = 0; mt < 4; ++mt) {
        const int off = ((qtile * 2 + (mt >> 1)) * 64 + (2 * (mt & 1) + (q4 >> 1)) * 16 + n15) * 8
                        + (q4 & 1) * 4;
        uint2 sq, sk;
        sq.x = cvt2(acc[mt][t][0], acc[mt][t][1]);
        sq.y = cvt2(acc[mt][t][2], acc[mt][t][3]);
        sk.x = cvt2(acc[4 + mt][t][0], acc[4 + mt][t][1]);
        sk.y = cvt2(acc[4 + mt][t][2], acc[4 + mt][t][3]);
        *reinterpret_cast<uint2*>(&q_l[off]) = sq;
        *reinterpret_cast<uint2*>(&k_l[off]) = sk;
      }
      // v: token s = s0 + e (s0 = rb + q4*4), feature h = nt*16 + n15
      const int s0 = rb + q4 * 4;
#pragma unroll
      for (int nt = 0; nt < 4; ++nt) {
        const int off = (((s0 >> 5) * 4 + nt) * 64 + ((s0 >> 3) & 3) * 16 + n15) * 8 + (s0 & 7);
        uint2 sv;
        sv.x = cvt2(acc[8 + nt][t][0], acc[8 + nt][t][1]);
        sv.y = cvt2(acc[8 + nt][t][2], acc[8 + nt][t][3]);
        *reinterpret_cast<uint2*>(&v_l[off]) = sv;
      }
    }
  }
  __syncthreads();

  // ======================= Phase 2: attention =======================
  // Wave wv owns q-tiles {wv, 15-wv}: 17 column-tiles each (balanced).
  const int laneA = ((q4 & 1) << 5) + n15;    // P-frag source lane
  const bool hi = (q4 >> 1) != 0;             // select odd tile of the pair
#pragma unroll
  for (int half = 0; half < 2; ++half) {
    const int qt = half ? (15 - wv) : wv;

    const s16x8 qf0 = *reinterpret_cast<const s16x8*>(&q_l[(qt * 2 + 0) * 512 + lane * 8]);
    const s16x8 qf1 = *reinterpret_cast<const s16x8*>(&q_l[(qt * 2 + 1) * 512 + lane * 8]);

    uint2 pk[16];              // packed exp(S^T) tiles
    float psum = 0.f;
    s16x8 kf0 = *reinterpret_cast<const s16x8*>(&k_l[0 * 512 + lane * 8]);
    s16x8 kf1 = *reinterpret_cast<const s16x8*>(&k_l[1 * 512 + lane * 8]);
#pragma unroll 16
    for (int ct = 0; ct < 16; ++ct) {
      if (ct > qt) break;
      const int nc = (ct < qt) ? ct + 1 : ct;   // clamped prefetch
      s16x8 nf0 = *reinterpret_cast<const s16x8*>(&k_l[(nc * 2 + 0) * 512 + lane * 8]);
      s16x8 nf1 = *reinterpret_cast<const s16x8*>(&k_l[(nc * 2 + 1) * 512 + lane * 8]);
      f32x4 a = (f32x4){0.f, 0.f, 0.f, 0.f};
      a = MFMA16(kf0, qf0, a);                  // S^T: rows s, cols m
      a = MFMA16(kf1, qf1, a);
      const bool diag = (ct == qt);
      float p[4];
#pragma unroll
      for (int e = 0; e < 4; ++e) {
        p[e] = (diag && (q4 * 4 + e > n15)) ? 0.f : __expf(a[e]);  // mask s > m
        psum += p[e];
      }
      pk[ct].x = cvt2(p[0], p[1]);
      pk[ct].y = cvt2(p[2], p[3]);
      kf0 = nf0; kf1 = nf1;
    }
    psum += __shfl_xor(psum, 16);
    psum += __shfl_xor(psum, 32);
    const float rn_col = 1.0f / psum;           // row sum for m = n15

    // O = P @ V (V^T frags from LDS); P-frag assembled via shuffles.
    f32x4 O[4];
#pragma unroll
    for (int nt = 0; nt < 4; ++nt) O[nt] = (f32x4){0.f, 0.f, 0.f, 0.f};
    const int nk = (qt + 2) >> 1;               // ceil(16*(qt+1)/32)
    s16x8 vf[4], vn[4];
#pragma unroll
    for (int nt = 0; nt < 4; ++nt)
      vf[nt] = *reinterpret_cast<const s16x8*>(&v_l[nt * 512 + lane * 8]);
#pragma unroll 8
    for (int kc = 0; kc < 8; ++kc) {
      if (kc >= nk) break;
      const int ncc = (kc + 1 < nk) ? kc + 1 : kc;
#pragma unroll
      for (int nt = 0; nt < 4; ++nt)
        vn[nt] = *reinterpret_cast<const s16x8*>(&v_l[(ncc * 4 + nt) * 512 + lane * 8]);
      const uint2 t0 = pk[2 * kc];
      const uint2 t1 = (2 * kc + 1 <= qt) ? pk[2 * kc + 1] : make_uint2(0u, 0u);
      unsigned r0a = __shfl(t0.x, laneA),      r0b = __shfl(t0.y, laneA);
      unsigned r0c = __shfl(t0.x, laneA + 16), r0d = __shfl(t0.y, laneA + 16);
      unsigned r1a = __shfl(t1.x, laneA),      r1b = __shfl(t1.y, laneA);
      unsigned r1c = __shfl(t1.x, laneA + 16), r1d = __shfl(t1.y, laneA + 16);
      u32x4 u;
      u[0] = hi ? r1a : r0a; u[1] = hi ? r1b : r0b;
      u[2] = hi ? r1c : r0c; u[3] = hi ? r1d : r0d;
      s16x8 pf = __builtin_bit_cast(s16x8, u);  // A[m=n15][s=32kc+q4*8+j]
#pragma unroll
      for (int nt = 0; nt < 4; ++nt) {
        O[nt] = MFMA16(pf, vf[nt], O[nt]);
        vf[nt] = vn[nt];
      }
    }
    float rnm[4];
#pragma unroll
    for (int e = 0; e < 4; ++e) rnm[e] = __shfl(rn_col, q4 * 4 + e);
#pragma unroll
    for (int nt = 0; nt < 4; ++nt)
#pragma unroll
      for (int e = 0; e < 4; ++e)
        out[(size_t)(b * 256 + qt * 16 + q4 * 4 + e) * 64 + nt * 16 + n15] = O[nt][e] * rnm[e];
  }
}

extern "C" void kernel_launch(void* const* d_in, const int* in_sizes, int n_in,
                              void* d_out, int out_size, void* d_ws, size_t ws_size,
                              hipStream_t stream) {
  const float* x  = (const float*)d_in[0];
  const float* Wq = (const float*)d_in[1];
  const float* Wk = (const float*)d_in[2];
  const float* Wv = (const float*)d_in[3];
  float* out = (float*)d_out;

  unsigned short* Wt_sw = (unsigned short*)d_ws;  // 73728 bf16 = 144 KB

  wcvt<<<288, 256, 0, stream>>>(Wq, Wk, Wv, Wt_sw);
  fused_attn<<<256, 512, 0, stream>>>(x, Wt_sw, out);
}

// Round 7
// 173.598 us; speedup vs baseline: 1.1611x; 1.1171x over previous
//
#include <hip/hip_runtime.h>

// ---------------------------------------------------------------------------
// AttentionHead: out = softmax(mask(q k^T / sqrt(384))) v, q/k/v = x @ W{q,k,v}
// B=256, T=256, C=384, H=64.
// FUSED: one block per batch (512 thr, 8 waves, 1 block/CU).
//   Phase 1: per-wave 32-token QKV projection. W chunk (12 KB) staged in LDS
//            ONCE per block per kc (cooperative, 1-deep reg prefetch) — cuts
//            global W traffic 8x (295 MB -> 37 MB; R6 was at the ~6 TB/s
//            mixed-cache ceiling moving 400 MB). q/k/v stored frag-linear in
//            LDS. x read with 1-deep reg prefetch (100 MB aggregate).
//   Phase 2: per-wave q-tiles {w, 15-w} (17 col-tiles each, balanced).
//            S^T = MFMA(A=K,B=Q) so P's C->A transform is 8 register shuffles
//            per 32-chunk; exp fused (no max pass; logits bounded); PV from
//            LDS V^T frags.
// Frag-linear: lane l's 16-B fragment of chunk c at base + c*1024 + l*16.
//   Wt_sw : [kc:12][nt:12][lane:64][j:8] (nt<4: q-feats x 1/sqrt(384), <8: k, else v)
//   q/k LDS: [tile:16][kc:2][lane:64][j:8]   v LDS: [kc:8][nt:4][lane:64][j:8]
// ---------------------------------------------------------------------------

typedef short s16x8 __attribute__((ext_vector_type(8)));   // 8 x bf16 raw bits
typedef float f32x4 __attribute__((ext_vector_type(4)));
typedef float f32x2 __attribute__((ext_vector_type(2)));
typedef unsigned u32x4 __attribute__((ext_vector_type(4)));
typedef __bf16 bf16x2t __attribute__((ext_vector_type(2)));

#define MFMA16(a, b, c) __builtin_amdgcn_mfma_f32_16x16x32_bf16((a), (b), (c), 0, 0, 0)

__device__ __forceinline__ unsigned short f2bf(float f) {
  return __builtin_bit_cast(unsigned short, (__bf16)f);     // v_cvt bf16 (RNE)
}
__device__ __forceinline__ unsigned cvt2(float a, float b) { // 2 f32 -> packed bf16x2
  f32x2 t; t[0] = a; t[1] = b;
  bf16x2t r = __builtin_convertvector(t, bf16x2t);
  return __builtin_bit_cast(unsigned, r);
}
__device__ __forceinline__ s16x8 cvt8(float4 a, float4 b) { // 8 f32 -> bf16 frag
  u32x4 u;
  u[0] = cvt2(a.x, a.y); u[1] = cvt2(a.z, a.w);
  u[2] = cvt2(b.x, b.y); u[3] = cvt2(b.z, b.w);
  return __builtin_bit_cast(s16x8, u);
}

// ---------------------------------------------------------------------------
// Kernel 0: build frag-linear Wt_sw from fp32 Wq/Wk/Wv.
// ---------------------------------------------------------------------------
__global__ __launch_bounds__(256) void wcvt(
    const float* __restrict__ Wq, const float* __restrict__ Wk,
    const float* __restrict__ Wv, unsigned short* __restrict__ Wt_sw) {
  int idx = blockIdx.x * 256 + threadIdx.x;   // 73728 = 12*12*64*8
  int j = idx & 7;
  int c = idx >> 3;
  int n15 = c & 15;
  int q4 = (c >> 4) & 3;
  int g = c >> 6;
  int nt = g % 12;
  int kc = g / 12;
  int n = nt * 16 + n15;                      // output feature 0..191
  int kk = kc * 32 + q4 * 8 + j;              // reduction index 0..383
  const float* src = (n < 64) ? Wq : (n < 128) ? Wk : Wv;
  float v = src[kk * 64 + (n & 63)];
  if (n < 64) v *= 0.05103103630798287f;      // fold 1/sqrt(384) into Wq
  Wt_sw[idx] = f2bf(v);
}

// ---------------------------------------------------------------------------
// Fused kernel: one block per batch.
// ---------------------------------------------------------------------------
__global__ __launch_bounds__(512) void fused_attn(
    const float* __restrict__ x, const unsigned short* __restrict__ Wt_sw,
    float* __restrict__ out) {
  __shared__ __align__(16) unsigned short q_l[16384];   // 32 KB
  __shared__ __align__(16) unsigned short k_l[16384];   // 32 KB
  __shared__ __align__(16) unsigned short v_l[16384];   // 32 KB (V^T frags)
  __shared__ __align__(16) unsigned short w_l[6144];    // 12 KB: one W chunk
  const int b = blockIdx.x;
  const int tid = threadIdx.x;
  const int wv = tid >> 6;                // 0..7
  const int lane = tid & 63;
  const int n15 = lane & 15;
  const int q4 = lane >> 4;

  // ======================= Phase 1: QKV -> LDS =======================
  // Wave wv projects tokens rb0 .. rb0+31 (tiles 2wv, 2wv+1).
  {
    const int rb0 = wv * 32;
    f32x4 acc[12][2];
#pragma unroll
    for (int i = 0; i < 12; ++i)
#pragma unroll
      for (int t = 0; t < 2; ++t) acc[i][t] = (f32x4){0.f, 0.f, 0.f, 0.f};

    const float* xp0 = x + ((long)b * 256 + rb0 + n15) * 384 + q4 * 8;
    const float* xp1 = xp0 + 16 * 384;
    float4 c00 = *reinterpret_cast<const float4*>(xp0);
    float4 c01 = *reinterpret_cast<const float4*>(xp0 + 4);
    float4 c10 = *reinterpret_cast<const float4*>(xp1);
    float4 c11 = *reinterpret_cast<const float4*>(xp1 + 4);

    // W chunk 0 prefetch into regs (cooperative: 768 uint4 per 12 KB chunk)
    const uint4* Wv4 = reinterpret_cast<const uint4*>(Wt_sw);
    uint4* wl4 = reinterpret_cast<uint4*>(w_l);
    uint4 wpa = Wv4[tid];
    uint4 wpb;
    if (tid < 256) wpb = Wv4[512 + tid];

    for (int kc = 0; kc < 12; ++kc) {
      __syncthreads();                    // all waves done reading chunk kc-1
      wl4[tid] = wpa;
      if (tid < 256) wl4[512 + tid] = wpb;
      __syncthreads();                    // chunk kc visible

      // prefetch chunk kc+1 and x columns kc+1
      const int nkc = (kc < 11) ? kc + 1 : 11;
      wpa = Wv4[nkc * 768 + tid];
      if (tid < 256) wpb = Wv4[nkc * 768 + 512 + tid];
      float4 p00 = *reinterpret_cast<const float4*>(xp0 + nkc * 32);
      float4 p01 = *reinterpret_cast<const float4*>(xp0 + nkc * 32 + 4);
      float4 p10 = *reinterpret_cast<const float4*>(xp1 + nkc * 32);
      float4 p11 = *reinterpret_cast<const float4*>(xp1 + nkc * 32 + 4);

      s16x8 xa[2];
      xa[0] = cvt8(c00, c01);
      xa[1] = cvt8(c10, c11);

#pragma unroll
      for (int nt = 0; nt < 12; ++nt) {
        s16x8 wf = *reinterpret_cast<const s16x8*>(&w_l[nt * 512 + lane * 8]);
        if (nt < 8) {
          acc[nt][0] = MFMA16(wf, xa[0], acc[nt][0]);   // q/k: features on m
          acc[nt][1] = MFMA16(wf, xa[1], acc[nt][1]);
        } else {
          acc[nt][0] = MFMA16(xa[0], wf, acc[nt][0]);   // v: tokens on m
          acc[nt][1] = MFMA16(xa[1], wf, acc[nt][1]);
        }
      }
      c00 = p00; c01 = p01; c10 = p10; c11 = p11;
    }

    // Epilogue: frag-linear q/k/v into LDS (8-B packed stores).
#pragma unroll
    for (int t = 0; t < 2; ++t) {
      const int rb = rb0 + t * 16;
      const int qtile = rb >> 4;     // = 2*wv + t
      // q/k: token = rb + n15, feature f = mt*16 + q4*4 + e
#pragma unroll
      for (int mt = 0; mt < 4; ++mt) {
        const int off = ((qtile * 2 + (mt >> 1)) * 64 + (2 * (mt & 1) + (q4 >> 1)) * 16 + n15) * 8
                        + (q4 & 1) * 4;
        uint2 sq, sk;
        sq.x = cvt2(acc[mt][t][0], acc[mt][t][1]);
        sq.y = cvt2(acc[mt][t][2], acc[mt][t][3]);
        sk.x = cvt2(acc[4 + mt][t][0], acc[4 + mt][t][1]);
        sk.y = cvt2(acc[4 + mt][t][2], acc[4 + mt][t][3]);
        *reinterpret_cast<uint2*>(&q_l[off]) = sq;
        *reinterpret_cast<uint2*>(&k_l[off]) = sk;
      }
      // v: token s = s0 + e (s0 = rb + q4*4), feature h = nt*16 + n15
      const int s0 = rb + q4 * 4;
#pragma unroll
      for (int nt = 0; nt < 4; ++nt) {
        const int off = (((s0 >> 5) * 4 + nt) * 64 + ((s0 >> 3) & 3) * 16 + n15) * 8 + (s0 & 7);
        uint2 sv;
        sv.x = cvt2(acc[8 + nt][t][0], acc[8 + nt][t][1]);
        sv.y = cvt2(acc[8 + nt][t][2], acc[8 + nt][t][3]);
        *reinterpret_cast<uint2*>(&v_l[off]) = sv;
      }
    }
  }
  __syncthreads();

  // ======================= Phase 2: attention =======================
  // Wave wv owns q-tiles {wv, 15-wv}: 17 column-tiles each (balanced).
  const int laneA = ((q4 & 1) << 5) + n15;    // P-frag source lane
  const bool hi = (q4 >> 1) != 0;             // select odd tile of the pair
#pragma unroll
  for (int half = 0; half < 2; ++half) {
    const int qt = half ? (15 - wv) : wv;

    const s16x8 qf0 = *reinterpret_cast<const s16x8*>(&q_l[(qt * 2 + 0) * 512 + lane * 8]);
    const s16x8 qf1 = *reinterpret_cast<const s16x8*>(&q_l[(qt * 2 + 1) * 512 + lane * 8]);

    uint2 pk[16];              // packed exp(S^T) tiles
    float psum = 0.f;
    s16x8 kf0 = *reinterpret_cast<const s16x8*>(&k_l[0 * 512 + lane * 8]);
    s16x8 kf1 = *reinterpret_cast<const s16x8*>(&k_l[1 * 512 + lane * 8]);
#pragma unroll 16
    for (int ct = 0; ct < 16; ++ct) {
      if (ct > qt) break;
      const int nc = (ct < qt) ? ct + 1 : ct;   // clamped prefetch
      s16x8 nf0 = *reinterpret_cast<const s16x8*>(&k_l[(nc * 2 + 0) * 512 + lane * 8]);
      s16x8 nf1 = *reinterpret_cast<const s16x8*>(&k_l[(nc * 2 + 1) * 512 + lane * 8]);
      f32x4 a = (f32x4){0.f, 0.f, 0.f, 0.f};
      a = MFMA16(kf0, qf0, a);                  // S^T: rows s, cols m
      a = MFMA16(kf1, qf1, a);
      const bool diag = (ct == qt);
      float p[4];
#pragma unroll
      for (int e = 0; e < 4; ++e) {
        p[e] = (diag && (q4 * 4 + e > n15)) ? 0.f : __expf(a[e]);  // mask s > m
        psum += p[e];
      }
      pk[ct].x = cvt2(p[0], p[1]);
      pk[ct].y = cvt2(p[2], p[3]);
      kf0 = nf0; kf1 = nf1;
    }
    psum += __shfl_xor(psum, 16);
    psum += __shfl_xor(psum, 32);
    const float rn_col = 1.0f / psum;           // row sum for m = n15

    // O = P @ V (V^T frags from LDS); P-frag assembled via shuffles.
    f32x4 O[4];
#pragma unroll
    for (int nt = 0; nt < 4; ++nt) O[nt] = (f32x4){0.f, 0.f, 0.f, 0.f};
    const int nk = (qt + 2) >> 1;               // ceil(16*(qt+1)/32)
    s16x8 vf[4], vn[4];
#pragma unroll
    for (int nt = 0; nt < 4; ++nt)
      vf[nt] = *reinterpret_cast<const s16x8*>(&v_l[nt * 512 + lane * 8]);
#pragma unroll 8
    for (int kc = 0; kc < 8; ++kc) {
      if (kc >= nk) break;
      const int ncc = (kc + 1 < nk) ? kc + 1 : kc;
#pragma unroll
      for (int nt = 0; nt < 4; ++nt)
        vn[nt] = *reinterpret_cast<const s16x8*>(&v_l[(ncc * 4 + nt) * 512 + lane * 8]);
      const uint2 t0 = pk[2 * kc];
      const uint2 t1 = (2 * kc + 1 <= qt) ? pk[2 * kc + 1] : make_uint2(0u, 0u);
      unsigned r0a = __shfl(t0.x, laneA),      r0b = __shfl(t0.y, laneA);
      unsigned r0c = __shfl(t0.x, laneA + 16), r0d = __shfl(t0.y, laneA + 16);
      unsigned r1a = __shfl(t1.x, laneA),      r1b = __shfl(t1.y, laneA);
      unsigned r1c = __shfl(t1.x, laneA + 16), r1d = __shfl(t1.y, laneA + 16);
      u32x4 u;
      u[0] = hi ? r1a : r0a; u[1] = hi ? r1b : r0b;
      u[2] = hi ? r1c : r0c; u[3] = hi ? r1d : r0d;
      s16x8 pf = __builtin_bit_cast(s16x8, u);  // A[m=n15][s=32kc+q4*8+j]
#pragma unroll
      for (int nt = 0; nt < 4; ++nt) {
        O[nt] = MFMA16(pf, vf[nt], O[nt]);
        vf[nt] = vn[nt];
      }
    }
    float rnm[4];
#pragma unroll
    for (int e = 0; e < 4; ++e) rnm[e] = __shfl(rn_col, q4 * 4 + e);
#pragma unroll
    for (int nt = 0; nt < 4; ++nt)
#pragma unroll
      for (int e = 0; e < 4; ++e)
        out[(size_t)(b * 256 + qt * 16 + q4 * 4 + e) * 64 + nt * 16 + n15] = O[nt][e] * rnm[e];
  }
}

extern "C" void kernel_launch(void* const* d_in, const int* in_sizes, int n_in,
                              void* d_out, int out_size, void* d_ws, size_t ws_size,
                              hipStream_t stream) {
  const float* x  = (const float*)d_in[0];
  const float* Wq = (const float*)d_in[1];
  const float* Wk = (const float*)d_in[2];
  const float* Wv = (const float*)d_in[3];
  float* out = (float*)d_out;

  unsigned short* Wt_sw = (unsigned short*)d_ws;  // 73728 bf16 = 144 KB

  wcvt<<<288, 256, 0, stream>>>(Wq, Wk, Wv, Wt_sw);
  fused_attn<<<256, 512, 0, stream>>>(x, Wt_sw, out);
}

// Round 8
// 167.393 us; speedup vs baseline: 1.2041x; 1.0371x over previous
//
#include <hip/hip_runtime.h>

// ---------------------------------------------------------------------------
// AttentionHead: out = softmax(mask(q k^T / sqrt(384))) v, q/k/v = x @ W{q,k,v}
// B=256, T=256, C=384, H=64.
// FUSED: one block per batch, 1024 thr (16 waves = 4/SIMD), 1 block/CU.
//   Phase 1: wave w projects token-tile w (16 tokens). W chunk (12 KB) staged
//            in double-buffered LDS (ONE barrier per kc, 13 total). x read
//            with depth-2 register prefetch. k/v stored frag-linear in LDS;
//            q stays in REGISTERS (converted C->B-operand layout by the
//            verified 8-shuffle transform; phase-2 tile w == phase-1 tile w).
//   Phase 2: wave w owns q-tile w. QK^T + exp + PV merged in one loop
//            (no max pass; logits bounded). S^T = MFMA(A=K,B=Q) so the P
//            C->A transform is 8 register shuffles per 32-chunk. Independent
//            MFMA pair + vector add (no C-dependency chain).
// Frag-linear: lane l's 16-B fragment of chunk c at base + c*1024 + l*16.
//   Wt_sw : [kc:12][nt:12][lane:64][j:8] (nt<4: q-feats x 1/sqrt(384), <8: k, else v)
//   k LDS: [tile:16][kc:2][lane:64][j:8]   v LDS: [kc:8][nt:4][lane:64][j:8]
// ---------------------------------------------------------------------------

typedef short s16x8 __attribute__((ext_vector_type(8)));   // 8 x bf16 raw bits
typedef float f32x4 __attribute__((ext_vector_type(4)));
typedef float f32x2 __attribute__((ext_vector_type(2)));
typedef unsigned u32x4 __attribute__((ext_vector_type(4)));
typedef __bf16 bf16x2t __attribute__((ext_vector_type(2)));

#define MFMA16(a, b, c) __builtin_amdgcn_mfma_f32_16x16x32_bf16((a), (b), (c), 0, 0, 0)

__device__ __forceinline__ unsigned short f2bf(float f) {
  return __builtin_bit_cast(unsigned short, (__bf16)f);     // RNE
}
__device__ __forceinline__ unsigned cvt2(float a, float b) { // 2 f32 -> packed bf16x2
  f32x2 t; t[0] = a; t[1] = b;
  bf16x2t r = __builtin_convertvector(t, bf16x2t);
  return __builtin_bit_cast(unsigned, r);
}
__device__ __forceinline__ s16x8 cvt8(float4 a, float4 b) { // 8 f32 -> bf16 frag
  u32x4 u;
  u[0] = cvt2(a.x, a.y); u[1] = cvt2(a.z, a.w);
  u[2] = cvt2(b.x, b.y); u[3] = cvt2(b.z, b.w);
  return __builtin_bit_cast(s16x8, u);
}
// C-layout tile pair (packed bf16x2) -> A/B-operand fragment (verified R5-R7)
__device__ __forceinline__ s16x8 asm_frag(uint2 t0, uint2 t1, int laneA, bool hi) {
  unsigned r0a = __shfl(t0.x, laneA),      r0b = __shfl(t0.y, laneA);
  unsigned r0c = __shfl(t0.x, laneA + 16), r0d = __shfl(t0.y, laneA + 16);
  unsigned r1a = __shfl(t1.x, laneA),      r1b = __shfl(t1.y, laneA);
  unsigned r1c = __shfl(t1.x, laneA + 16), r1d = __shfl(t1.y, laneA + 16);
  u32x4 u;
  u[0] = hi ? r1a : r0a; u[1] = hi ? r1b : r0b;
  u[2] = hi ? r1c : r0c; u[3] = hi ? r1d : r0d;
  return __builtin_bit_cast(s16x8, u);
}

// ---------------------------------------------------------------------------
// Kernel 0: build frag-linear Wt_sw from fp32 Wq/Wk/Wv.
// ---------------------------------------------------------------------------
__global__ __launch_bounds__(256) void wcvt(
    const float* __restrict__ Wq, const float* __restrict__ Wk,
    const float* __restrict__ Wv, unsigned short* __restrict__ Wt_sw) {
  int idx = blockIdx.x * 256 + threadIdx.x;   // 73728 = 12*12*64*8
  int j = idx & 7;
  int c = idx >> 3;
  int n15 = c & 15;
  int q4 = (c >> 4) & 3;
  int g = c >> 6;
  int nt = g % 12;
  int kc = g / 12;
  int n = nt * 16 + n15;                      // output feature 0..191
  int kk = kc * 32 + q4 * 8 + j;              // reduction index 0..383
  const float* src = (n < 64) ? Wq : (n < 128) ? Wk : Wv;
  float v = src[kk * 64 + (n & 63)];
  if (n < 64) v *= 0.05103103630798287f;      // fold 1/sqrt(384) into Wq
  Wt_sw[idx] = f2bf(v);
}

// ---------------------------------------------------------------------------
// Fused kernel: one block per batch, 16 waves.
// ---------------------------------------------------------------------------
__global__ __launch_bounds__(1024, 4) void fused_attn(
    const float* __restrict__ x, const unsigned short* __restrict__ Wt_sw,
    float* __restrict__ out) {
  __shared__ __align__(16) unsigned short k_l[16384];   // 32 KB
  __shared__ __align__(16) unsigned short v_l[16384];   // 32 KB (V^T frags)
  __shared__ __align__(16) unsigned short w_l[12288];   // 24 KB: W chunk dbuf
  const int b = blockIdx.x;
  const int tid = threadIdx.x;
  const int wv = tid >> 6;                // 0..15 = token tile = q-tile
  const int lane = tid & 63;
  const int n15 = lane & 15;
  const int q4 = lane >> 4;

  // ======================= Phase 1: QKV =======================
  f32x4 acc[12];
#pragma unroll
  for (int i = 0; i < 12; ++i) acc[i] = (f32x4){0.f, 0.f, 0.f, 0.f};

  const float* xp = x + ((long)b * 256 + wv * 16 + n15) * 384 + q4 * 8;
  float4 f0a = *reinterpret_cast<const float4*>(xp);
  float4 f0b = *reinterpret_cast<const float4*>(xp + 4);
  float4 f1a = *reinterpret_cast<const float4*>(xp + 32);
  float4 f1b = *reinterpret_cast<const float4*>(xp + 36);

  const uint4* Wv4 = reinterpret_cast<const uint4*>(Wt_sw);
  uint4* wl4 = reinterpret_cast<uint4*>(w_l);
  uint4 wreg;
  if (tid < 768) wreg = Wv4[tid];

  for (int kc = 0; kc < 12; ++kc) {
    if (tid < 768) wl4[(kc & 1) * 768 + tid] = wreg;
    __syncthreads();                      // single barrier per kc (dbuf-safe)
    if (kc < 11 && tid < 768) wreg = Wv4[(kc + 1) * 768 + tid];
    const int nkc = (kc < 10) ? kc + 2 : 11;        // depth-2 x prefetch
    float4 pa = *reinterpret_cast<const float4*>(xp + nkc * 32);
    float4 pb = *reinterpret_cast<const float4*>(xp + nkc * 32 + 4);

    s16x8 xa = cvt8(f0a, f0b);
    const unsigned short* wbuf = w_l + (kc & 1) * 6144;
#pragma unroll
    for (int nt = 0; nt < 12; ++nt) {
      s16x8 wf = *reinterpret_cast<const s16x8*>(&wbuf[nt * 512 + lane * 8]);
      if (nt < 8) acc[nt] = MFMA16(wf, xa, acc[nt]);  // q/k: features on m
      else        acc[nt] = MFMA16(xa, wf, acc[nt]);  // v: tokens on m
    }
    f0a = f1a; f0b = f1b; f1a = pa; f1b = pb;
  }

  // q (acc[0..3]) -> packed C-layout pairs, stays in registers
  uint2 pkq[4];
#pragma unroll
  for (int mt = 0; mt < 4; ++mt) {
    pkq[mt].x = cvt2(acc[mt][0], acc[mt][1]);
    pkq[mt].y = cvt2(acc[mt][2], acc[mt][3]);
  }
  // k/v -> frag-linear LDS (8-B packed stores)
#pragma unroll
  for (int mt = 0; mt < 4; ++mt) {
    const int off = ((wv * 2 + (mt >> 1)) * 64 + (2 * (mt & 1) + (q4 >> 1)) * 16 + n15) * 8
                    + (q4 & 1) * 4;
    uint2 sk;
    sk.x = cvt2(acc[4 + mt][0], acc[4 + mt][1]);
    sk.y = cvt2(acc[4 + mt][2], acc[4 + mt][3]);
    *reinterpret_cast<uint2*>(&k_l[off]) = sk;
  }
  const int s0 = wv * 16 + q4 * 4;
#pragma unroll
  for (int nt = 0; nt < 4; ++nt) {
    const int off = (((s0 >> 5) * 4 + nt) * 64 + ((s0 >> 3) & 3) * 16 + n15) * 8 + (s0 & 7);
    uint2 sv;
    sv.x = cvt2(acc[8 + nt][0], acc[8 + nt][1]);
    sv.y = cvt2(acc[8 + nt][2], acc[8 + nt][3]);
    *reinterpret_cast<uint2*>(&v_l[off]) = sv;
  }

  // assemble q B-operand frags in registers (within-wave, pre-barrier OK)
  const int laneA = ((q4 & 1) << 5) + n15;
  const bool hi = (q4 >> 1) != 0;
  const s16x8 qf0 = asm_frag(pkq[0], pkq[1], laneA, hi);  // feats 0..31
  const s16x8 qf1 = asm_frag(pkq[2], pkq[3], laneA, hi);  // feats 32..63
  __syncthreads();

  // ======================= Phase 2: attention (tile qt = wv) ==============
  const int qt = wv;
  const f32x4 zf = (f32x4){0.f, 0.f, 0.f, 0.f};
  f32x4 O[4];
#pragma unroll
  for (int nt = 0; nt < 4; ++nt) O[nt] = zf;
  float psum = 0.f;
  const int nk = (qt + 2) >> 1;               // ceil((qt+1)/2)
#pragma unroll 8
  for (int kc = 0; kc < 8; ++kc) {
    if (kc >= nk) break;
    const int ct0 = 2 * kc;
    const bool has1 = (ct0 + 1 <= qt);        // wave-uniform
    s16x8 kf0 = *reinterpret_cast<const s16x8*>(&k_l[(ct0 * 2 + 0) * 512 + lane * 8]);
    s16x8 kf1 = *reinterpret_cast<const s16x8*>(&k_l[(ct0 * 2 + 1) * 512 + lane * 8]);
    f32x4 a0 = MFMA16(kf0, qf0, zf);          // independent pair, no C-chain
    f32x4 a1 = MFMA16(kf1, qf1, zf);
    uint2 t0, t1;
    {
      f32x4 s = a0 + a1;
      const bool diag = (ct0 == qt);
      float p[4];
#pragma unroll
      for (int e = 0; e < 4; ++e) {
        p[e] = (diag && (q4 * 4 + e > n15)) ? 0.f : __expf(s[e]);
        psum += p[e];
      }
      t0.x = cvt2(p[0], p[1]); t0.y = cvt2(p[2], p[3]);
    }
    if (has1) {
      const int ct1 = ct0 + 1;
      s16x8 kg0 = *reinterpret_cast<const s16x8*>(&k_l[(ct1 * 2 + 0) * 512 + lane * 8]);
      s16x8 kg1 = *reinterpret_cast<const s16x8*>(&k_l[(ct1 * 2 + 1) * 512 + lane * 8]);
      f32x4 b0 = MFMA16(kg0, qf0, zf);
      f32x4 b1 = MFMA16(kg1, qf1, zf);
      f32x4 s = b0 + b1;
      const bool diag = (ct1 == qt);
      float p[4];
#pragma unroll
      for (int e = 0; e < 4; ++e) {
        p[e] = (diag && (q4 * 4 + e > n15)) ? 0.f : __expf(s[e]);
        psum += p[e];
      }
      t1.x = cvt2(p[0], p[1]); t1.y = cvt2(p[2], p[3]);
    } else {
      t1 = make_uint2(0u, 0u);
    }
    s16x8 pf = asm_frag(t0, t1, laneA, hi);   // A[m=n15][s=32kc+q4*8+j]
#pragma unroll
    for (int nt = 0; nt < 4; ++nt) {
      s16x8 vf = *reinterpret_cast<const s16x8*>(&v_l[(kc * 4 + nt) * 512 + lane * 8]);
      O[nt] = MFMA16(pf, vf, O[nt]);
    }
  }
  psum += __shfl_xor(psum, 16);
  psum += __shfl_xor(psum, 32);
  const float rn_col = 1.0f / psum;           // row sum for m = n15
  float rnm[4];
#pragma unroll
  for (int e = 0; e < 4; ++e) rnm[e] = __shfl(rn_col, q4 * 4 + e);
#pragma unroll
  for (int nt = 0; nt < 4; ++nt)
#pragma unroll
    for (int e = 0; e < 4; ++e)
      out[(size_t)(b * 256 + qt * 16 + q4 * 4 + e) * 64 + nt * 16 + n15] = O[nt][e] * rnm[e];
}

extern "C" void kernel_launch(void* const* d_in, const int* in_sizes, int n_in,
                              void* d_out, int out_size, void* d_ws, size_t ws_size,
                              hipStream_t stream) {
  const float* x  = (const float*)d_in[0];
  const float* Wq = (const float*)d_in[1];
  const float* Wk = (const float*)d_in[2];
  const float* Wv = (const float*)d_in[3];
  float* out = (float*)d_out;

  unsigned short* Wt_sw = (unsigned short*)d_ws;  // 73728 bf16 = 144 KB

  wcvt<<<288, 256, 0, stream>>>(Wq, Wk, Wv, Wt_sw);
  fused_attn<<<256, 1024, 0, stream>>>(x, Wt_sw, out);
}